// Round 2
// baseline (1005.564 us; speedup 1.0000x reference)
//
#include <hip/hip_runtime.h>
#include <hip/hip_bf16.h>

#define DD 128
#define LN_EPS 1e-5f
#define BCAP 3072   // per-bin record cap (avg 2048, +22 sigma)

typedef __bf16 bf16x8 __attribute__((ext_vector_type(8)));
typedef float f32x4 __attribute__((ext_vector_type(4)));

__device__ __forceinline__ float bflo(unsigned int u) { return __uint_as_float(u << 16); }
__device__ __forceinline__ float bfhi(unsigned int u) { return __uint_as_float(u & 0xffff0000u); }

// ---- feat fp32 -> bf16 (vectorized, 8 elems/thread) ----
__global__ __launch_bounds__(256) void k_pack_feat(const float* __restrict__ f,
                                                   unsigned short* __restrict__ fb, int n8) {
    int i = blockIdx.x * 256 + threadIdx.x;
    if (i >= n8) return;
    const float4* p = (const float4*)f + (size_t)i * 2;
    float4 v0 = p[0], v1 = p[1];
    float vv[8] = {v0.x, v0.y, v0.z, v0.w, v1.x, v1.y, v1.z, v1.w};
    unsigned short u[8];
#pragma unroll
    for (int j = 0; j < 8; j++) {
        __hip_bfloat16 b = __float2bfloat16(vv[j]);
        u[j] = *reinterpret_cast<unsigned short*>(&b);
    }
    uint4 o;
    o.x = u[0] | ((unsigned)u[1] << 16);
    o.y = u[2] | ((unsigned)u[3] << 16);
    o.z = u[4] | ((unsigned)u[5] << 16);
    o.w = u[6] | ((unsigned)u[7] << 16);
    ((uint4*)fb)[i] = o;
}

// ---- weights -> bf16, column-major concat [t][col 0..383][k 0..127] ----
__global__ __launch_bounds__(256) void k_pack_w(const float* __restrict__ W,
                                                const float* __restrict__ Wf,
                                                unsigned short* __restrict__ wcat) {
    int i = blockIdx.x * 256 + threadIdx.x;
    if (i >= 4 * 384 * 128) return;
    int t = i / (384 * 128);
    int r = i % (384 * 128);
    int c = r / 128, k = r % 128;
    float v = (c < 128) ? W[((size_t)t * 128 + k) * 128 + c]
                        : Wf[((size_t)t * 128 + k) * 256 + (c - 128)];
    __hip_bfloat16 b = __float2bfloat16(v);
    wcat[i] = *reinterpret_cast<unsigned short*>(&b);
}

// ---- A1: histogram edges per 128-node bin ----
__global__ __launch_bounds__(256) void k_hist(const int* __restrict__ dst,
                                              int* __restrict__ bincnt, int E4) {
    int i = blockIdx.x * 256 + threadIdx.x;
    if (i >= E4) return;
    atomicAdd(&bincnt[dst[i] >> 7], 1);
}

// ---- A2: exclusive scan over NB bins (NB <= 1024), one block ----
__global__ __launch_bounds__(1024) void k_scan(const int* __restrict__ cnt,
                                               int* __restrict__ off,
                                               int* __restrict__ fill, int NB) {
    __shared__ int s[1024];
    int tid = threadIdx.x;
    s[tid] = (tid < NB) ? cnt[tid] : 0;
    __syncthreads();
    for (int st = 1; st < 1024; st <<= 1) {
        int t = s[tid];
        int a = (tid >= st) ? s[tid - st] : 0;
        __syncthreads();
        s[tid] = t + a;
        __syncthreads();
    }
    if (tid < NB) {
        int excl = s[tid] - cnt[tid];
        off[tid] = excl;
        fill[tid] = excl;
        if (tid == NB - 1) off[NB] = s[tid];
    }
}

// ---- A3: place 4B records (dst&127)<<19 | (t*N+src) into bin streams ----
__global__ __launch_bounds__(256) void k_place(const int* __restrict__ src,
                                               const int* __restrict__ dst,
                                               int* __restrict__ fill,
                                               unsigned int* __restrict__ rec,
                                               int N, int E) {
    int i = blockIdx.x * 256 + threadIdx.x;
    if (i >= 4 * E) return;
    int d = dst[i];
    int t = i / E;
    unsigned int r = ((unsigned)(d & 127) << 19) | (unsigned)(t * N + src[i]);
    int pos = atomicAdd(&fill[d >> 7], 1);
    rec[pos] = r;
}

// ---- fused GEMM + FiLM: m_t = relu(gamma*msg + beta), bf16 out ----
__global__ __launch_bounds__(256, 2) void k_gemm_film(const unsigned short* __restrict__ featb,
                                                      const unsigned short* __restrict__ wcat,
                                                      unsigned short* __restrict__ m, int N) {
    __shared__ unsigned char smem[64 * 256];  // 64 rows x 128 bf16, XOR-swizzled
    const int t = blockIdx.y;
    const int r0 = blockIdx.x * 64;
    const int tid = threadIdx.x;

#pragma unroll
    for (int it = 0; it < 4; it++) {
        int c = tid + it * 256;
        int row = c >> 4;
        int kb = (c & 15) * 16;
        int gr = r0 + row;
        uint4 v = {0u, 0u, 0u, 0u};
        if (gr < N) v = *(const uint4*)((const unsigned char*)featb + (size_t)gr * 256 + kb);
        *(uint4*)(smem + row * 256 + (kb ^ ((row & 7) << 4))) = v;
    }
    __syncthreads();

    const int w = tid >> 6, lane = tid & 63;
    const int lr = lane & 15, kg = lane >> 4;
    const int cbase = w * 32;

    f32x4 accm[4][2] = {}, accg[4][2] = {}, accb[4][2] = {};
    const unsigned short* wt = wcat + (size_t)t * 384 * 128;

#pragma unroll
    for (int kk = 0; kk < 128; kk += 32) {
        bf16x8 a[4];
#pragma unroll
        for (int mi = 0; mi < 4; mi++) {
            int row = mi * 16 + lr;
            int kb = kk * 2 + kg * 16;
            a[mi] = *(const bf16x8*)(smem + row * 256 + (kb ^ ((row & 7) << 4)));
        }
        const int k0 = kk + kg * 8;
        bf16x8 bm[2], bg[2], bb[2];
#pragma unroll
        for (int cj = 0; cj < 2; cj++) {
            int col = cbase + cj * 16 + lr;
            bm[cj] = *(const bf16x8*)(wt + (size_t)col * 128 + k0);
            bg[cj] = *(const bf16x8*)(wt + (size_t)(128 + col) * 128 + k0);
            bb[cj] = *(const bf16x8*)(wt + (size_t)(256 + col) * 128 + k0);
        }
#pragma unroll
        for (int mi = 0; mi < 4; mi++)
#pragma unroll
            for (int cj = 0; cj < 2; cj++) {
                accm[mi][cj] = __builtin_amdgcn_mfma_f32_16x16x32_bf16(a[mi], bm[cj], accm[mi][cj], 0, 0, 0);
                accg[mi][cj] = __builtin_amdgcn_mfma_f32_16x16x32_bf16(a[mi], bg[cj], accg[mi][cj], 0, 0, 0);
                accb[mi][cj] = __builtin_amdgcn_mfma_f32_16x16x32_bf16(a[mi], bb[cj], accb[mi][cj], 0, 0, 0);
            }
    }

    unsigned short* mt = m + (size_t)t * N * DD;
#pragma unroll
    for (int mi = 0; mi < 4; mi++)
#pragma unroll
        for (int cj = 0; cj < 2; cj++)
#pragma unroll
            for (int r = 0; r < 4; r++) {
                int row = r0 + mi * 16 + kg * 4 + r;
                if (row < N) {
                    float v = accg[mi][cj][r] * accm[mi][cj][r] + accb[mi][cj][r];
                    v = fmaxf(v, 0.0f);
                    __hip_bfloat16 b = __float2bfloat16(v);
                    mt[(size_t)row * DD + cbase + cj * 16 + lr] =
                        *reinterpret_cast<unsigned short*>(&b);
                }
            }
}

// ---- B: per-bin LDS counting sort + gather + fused LayerNorm ----
__global__ __launch_bounds__(256) void k_sort_agg_ln(const unsigned int* __restrict__ rec,
                                                     const int* __restrict__ binoff,
                                                     const unsigned int* __restrict__ m32,
                                                     const float* __restrict__ lnw,
                                                     const float* __restrict__ lnb,
                                                     float* __restrict__ out, int N) {
    __shared__ int lcnt[128], soff[128], sfill[128], tmp[128];
    __shared__ unsigned int sorted[BCAP];
    const int b = blockIdx.x, tid = threadIdx.x;
    const int s0 = binoff[b];
    int n = binoff[b + 1] - s0;
    if (n > BCAP) n = BCAP;

    if (tid < 128) lcnt[tid] = 0;
    __syncthreads();
    for (int j = tid; j < n; j += 256) atomicAdd(&lcnt[rec[s0 + j] >> 19], 1);
    __syncthreads();
    if (tid < 128) tmp[tid] = lcnt[tid];
    __syncthreads();
    for (int st = 1; st < 128; st <<= 1) {
        int t = 0, a = 0;
        if (tid < 128) {
            t = tmp[tid];
            a = (tid >= st) ? tmp[tid - st] : 0;
        }
        __syncthreads();
        if (tid < 128) tmp[tid] = t + a;
        __syncthreads();
    }
    if (tid < 128) {
        int ex = tmp[tid] - lcnt[tid];
        soff[tid] = ex;
        sfill[tid] = ex;
    }
    __syncthreads();
    for (int j = tid; j < n; j += 256) {
        unsigned int r = rec[s0 + j];
        int p = atomicAdd(&sfill[r >> 19], 1);
        sorted[p] = r & 0x7FFFFu;
    }
    __syncthreads();

    const int wv = tid >> 6, lane = tid & 63;
#pragma unroll 1
    for (int i = 0; i < 32; i++) {
        int d7 = i * 4 + wv;
        int node = b * 128 + d7;
        if (node >= N) continue;  // wave-uniform branch
        int e0 = soff[d7], en = lcnt[d7];
        float a0 = 0.f, a1 = 0.f;
        int e = 0;
        for (; e + 2 <= en; e += 2) {
            unsigned g0 = sorted[e0 + e], g1 = sorted[e0 + e + 1];
            unsigned p0 = m32[(size_t)g0 * 64 + lane];
            unsigned p1 = m32[(size_t)g1 * 64 + lane];
            a0 += bflo(p0) + bflo(p1);
            a1 += bfhi(p0) + bfhi(p1);
        }
        if (e < en) {
            unsigned p0 = m32[(size_t)sorted[e0 + e] * 64 + lane];
            a0 += bflo(p0);
            a1 += bfhi(p0);
        }
        float sum = a0 + a1, ssq = a0 * a0 + a1 * a1;
#pragma unroll
        for (int o = 1; o < 64; o <<= 1) {
            sum += __shfl_xor(sum, o, 64);
            ssq += __shfl_xor(ssq, o, 64);
        }
        float mu = sum * (1.0f / 128.0f);
        float var = ssq * (1.0f / 128.0f) - mu * mu;
        float rstd = rsqrtf(var + LN_EPS);
        int d0 = lane * 2;
        float o0 = (a0 - mu) * rstd * lnw[d0] + lnb[d0];
        float o1 = (a1 - mu) * rstd * lnw[d0 + 1] + lnb[d0 + 1];
        *(float2*)(out + (size_t)node * DD + d0) = make_float2(o0, o1);
    }
}

extern "C" void kernel_launch(void* const* d_in, const int* in_sizes, int n_in,
                              void* d_out, int out_size, void* d_ws, size_t ws_size,
                              hipStream_t stream) {
    const float* feat = (const float*)d_in[0];
    const float* W    = (const float*)d_in[1];
    const float* Wf   = (const float*)d_in[2];
    const float* lnw  = (const float*)d_in[3];
    const float* lnb  = (const float*)d_in[4];
    const int* src    = (const int*)d_in[5];
    const int* dst    = (const int*)d_in[6];
    float* out = (float*)d_out;

    const int N = in_sizes[0] / DD;   // 100000
    const int E = in_sizes[5] / 4;    // 400000
    const int E4 = 4 * E;
    const int NB = (N + 127) >> 7;    // 782 bins

    size_t off = 0;
    char* ws = (char*)d_ws;
    auto alloc = [&](size_t bytes) -> void* {
        void* p = ws + off;
        off += (bytes + 255) & ~(size_t)255;
        return p;
    };
    unsigned short* m     = (unsigned short*)alloc((size_t)4 * N * DD * 2);  // 102.4 MB
    unsigned short* featb = (unsigned short*)alloc((size_t)N * DD * 2);      // 25.6 MB
    unsigned short* wcat  = (unsigned short*)alloc((size_t)4 * 384 * 128 * 2);
    int* bincnt = (int*)alloc((size_t)(NB + 1) * 4);
    int* binoff = (int*)alloc((size_t)(NB + 1) * 4);
    int* binfill = (int*)alloc((size_t)(NB + 1) * 4);
    unsigned int* rec = (unsigned int*)alloc((size_t)E4 * 4);                // 6.4 MB
    if (off > ws_size) return;

    hipMemsetAsync(bincnt, 0, (size_t)(NB + 1) * 4, stream);
    int n8 = N * DD / 8;
    k_pack_feat<<<(n8 + 255) / 256, 256, 0, stream>>>(feat, featb, n8);
    k_pack_w<<<(4 * 384 * 128 + 255) / 256, 256, 0, stream>>>(W, Wf, wcat);
    k_hist<<<(E4 + 255) / 256, 256, 0, stream>>>(dst, bincnt, E4);
    k_scan<<<1, 1024, 0, stream>>>(bincnt, binoff, binfill, NB);
    k_place<<<(E4 + 255) / 256, 256, 0, stream>>>(src, dst, binfill, rec, N, E);
    dim3 gg((N + 63) / 64, 4);
    k_gemm_film<<<gg, 256, 0, stream>>>(featb, wcat, m, N);
    k_sort_agg_ln<<<NB, 256, 0, stream>>>(rec, binoff, (const unsigned int*)m, lnw, lnb, out, N);
}

// Round 3
// 289.638 us; speedup vs baseline: 3.4718x; 3.4718x over previous
//
#include <hip/hip_runtime.h>
#include <hip/hip_bf16.h>

#define DD 128
#define LN_EPS 1e-5f
#define BCAP 3072      // per-bin record cap (avg 2048, +22 sigma)
#define MAXBIN 1024    // LDS histogram capacity (NBIN = 782 for N=100000)
#define CHUNK 4096     // edges per binning block

typedef __bf16 bf16x8 __attribute__((ext_vector_type(8)));
typedef float f32x4 __attribute__((ext_vector_type(4)));

__device__ __forceinline__ float bflo(unsigned int u) { return __uint_as_float(u << 16); }
__device__ __forceinline__ float bfhi(unsigned int u) { return __uint_as_float(u & 0xffff0000u); }

// ---- feat fp32 -> bf16 (vectorized, 8 elems/thread) ----
__global__ __launch_bounds__(256) void k_pack_feat(const float* __restrict__ f,
                                                   unsigned short* __restrict__ fb, int n8) {
    int i = blockIdx.x * 256 + threadIdx.x;
    if (i >= n8) return;
    const float4* p = (const float4*)f + (size_t)i * 2;
    float4 v0 = p[0], v1 = p[1];
    float vv[8] = {v0.x, v0.y, v0.z, v0.w, v1.x, v1.y, v1.z, v1.w};
    unsigned short u[8];
#pragma unroll
    for (int j = 0; j < 8; j++) {
        __hip_bfloat16 b = __float2bfloat16(vv[j]);
        u[j] = *reinterpret_cast<unsigned short*>(&b);
    }
    uint4 o;
    o.x = u[0] | ((unsigned)u[1] << 16);
    o.y = u[2] | ((unsigned)u[3] << 16);
    o.z = u[4] | ((unsigned)u[5] << 16);
    o.w = u[6] | ((unsigned)u[7] << 16);
    ((uint4*)fb)[i] = o;
}

// ---- weights -> bf16, column-major concat [t][col 0..383][k 0..127] ----
__global__ __launch_bounds__(256) void k_pack_w(const float* __restrict__ W,
                                                const float* __restrict__ Wf,
                                                unsigned short* __restrict__ wcat) {
    int i = blockIdx.x * 256 + threadIdx.x;
    if (i >= 4 * 384 * 128) return;
    int t = i / (384 * 128);
    int r = i % (384 * 128);
    int c = r / 128, k = r % 128;
    float v = (c < 128) ? W[((size_t)t * 128 + k) * 128 + c]
                        : Wf[((size_t)t * 128 + k) * 256 + (c - 128)];
    __hip_bfloat16 b = __float2bfloat16(v);
    wcat[i] = *reinterpret_cast<unsigned short*>(&b);
}

// ---- P1: per-block LDS histogram -> H[bin*NBLK + blk] ----
__global__ __launch_bounds__(256) void k_hist2(const int* __restrict__ dst,
                                               int* __restrict__ H, int E4, int NBLK, int NBIN) {
    __shared__ int h[MAXBIN];
    const int b = blockIdx.x;
    for (int j = threadIdx.x; j < NBIN; j += 256) h[j] = 0;
    __syncthreads();
    int base = b * CHUNK;
    int end = base + CHUNK < E4 ? base + CHUNK : E4;
    for (int i = base + threadIdx.x; i < end; i += 256) atomicAdd(&h[dst[i] >> 7], 1);
    __syncthreads();
    for (int j = threadIdx.x; j < NBIN; j += 256) H[(size_t)j * NBLK + b] = h[j];
}

// ---- P2: per-bin exclusive scan across blocks (one wave per bin), in place ----
__global__ __launch_bounds__(256) void k_scanbin(int* __restrict__ H, int* __restrict__ C,
                                                 int NBLK, int NBIN) {
    const int wv = (blockIdx.x * 256 + threadIdx.x) >> 6;
    const int lane = threadIdx.x & 63;
    if (wv >= NBIN) return;
    int* row = H + (size_t)wv * NBLK;
    int run = 0;
    for (int base = 0; base < NBLK; base += 64) {
        int idx = base + lane;
        int v = (idx < NBLK) ? row[idx] : 0;
        int s = v;
#pragma unroll
        for (int o = 1; o < 64; o <<= 1) {
            int u = __shfl_up(s, o, 64);
            if (lane >= o) s += u;
        }
        if (idx < NBLK) row[idx] = run + s - v;   // exclusive
        run += __shfl(s, 63, 64);
    }
    if (lane == 0) C[wv] = run;
}

// ---- P3: exclusive scan over NBIN bin totals (one block) ----
__global__ __launch_bounds__(1024) void k_scan(const int* __restrict__ cnt,
                                               int* __restrict__ off, int NB) {
    __shared__ int s[1024];
    int tid = threadIdx.x;
    s[tid] = (tid < NB) ? cnt[tid] : 0;
    __syncthreads();
    for (int st = 1; st < 1024; st <<= 1) {
        int t = s[tid];
        int a = (tid >= st) ? s[tid - st] : 0;
        __syncthreads();
        s[tid] = t + a;
        __syncthreads();
    }
    if (tid < NB) {
        off[tid] = s[tid] - cnt[tid];
        if (tid == NB - 1) off[NB] = s[tid];
    }
}

// ---- P4: place records at deterministic offsets; LDS atomics only ----
__global__ __launch_bounds__(256) void k_place2(const int* __restrict__ src,
                                                const int* __restrict__ dst,
                                                const int* __restrict__ H,
                                                const int* __restrict__ binoff,
                                                unsigned int* __restrict__ rec,
                                                int N, int E, int E4, int NBLK, int NBIN) {
    __shared__ int fill[MAXBIN];
    const int b = blockIdx.x;
    for (int j = threadIdx.x; j < NBIN; j += 256)
        fill[j] = binoff[j] + H[(size_t)j * NBLK + b];
    __syncthreads();
    int base = b * CHUNK;
    int end = base + CHUNK < E4 ? base + CHUNK : E4;
    for (int i = base + threadIdx.x; i < end; i += 256) {
        int d = dst[i];
        int t = i / E;
        unsigned int r = ((unsigned)(d & 127) << 19) | (unsigned)(t * N + src[i]);
        int pos = atomicAdd(&fill[d >> 7], 1);
        rec[pos] = r;
    }
}

// ---- fused GEMM + FiLM: m_t = relu(gamma*msg + beta), bf16 out ----
__global__ __launch_bounds__(256, 2) void k_gemm_film(const unsigned short* __restrict__ featb,
                                                      const unsigned short* __restrict__ wcat,
                                                      unsigned short* __restrict__ m, int N) {
    __shared__ unsigned char smem[64 * 256];  // 64 rows x 128 bf16, XOR-swizzled
    const int t = blockIdx.y;
    const int r0 = blockIdx.x * 64;
    const int tid = threadIdx.x;

#pragma unroll
    for (int it = 0; it < 4; it++) {
        int c = tid + it * 256;
        int row = c >> 4;
        int kb = (c & 15) * 16;
        int gr = r0 + row;
        uint4 v = {0u, 0u, 0u, 0u};
        if (gr < N) v = *(const uint4*)((const unsigned char*)featb + (size_t)gr * 256 + kb);
        *(uint4*)(smem + row * 256 + (kb ^ ((row & 7) << 4))) = v;
    }
    __syncthreads();

    const int w = tid >> 6, lane = tid & 63;
    const int lr = lane & 15, kg = lane >> 4;
    const int cbase = w * 32;

    f32x4 accm[4][2] = {}, accg[4][2] = {}, accb[4][2] = {};
    const unsigned short* wt = wcat + (size_t)t * 384 * 128;

#pragma unroll
    for (int kk = 0; kk < 128; kk += 32) {
        bf16x8 a[4];
#pragma unroll
        for (int mi = 0; mi < 4; mi++) {
            int row = mi * 16 + lr;
            int kb = kk * 2 + kg * 16;
            a[mi] = *(const bf16x8*)(smem + row * 256 + (kb ^ ((row & 7) << 4)));
        }
        const int k0 = kk + kg * 8;
        bf16x8 bm[2], bg[2], bb[2];
#pragma unroll
        for (int cj = 0; cj < 2; cj++) {
            int col = cbase + cj * 16 + lr;
            bm[cj] = *(const bf16x8*)(wt + (size_t)col * 128 + k0);
            bg[cj] = *(const bf16x8*)(wt + (size_t)(128 + col) * 128 + k0);
            bb[cj] = *(const bf16x8*)(wt + (size_t)(256 + col) * 128 + k0);
        }
#pragma unroll
        for (int mi = 0; mi < 4; mi++)
#pragma unroll
            for (int cj = 0; cj < 2; cj++) {
                accm[mi][cj] = __builtin_amdgcn_mfma_f32_16x16x32_bf16(a[mi], bm[cj], accm[mi][cj], 0, 0, 0);
                accg[mi][cj] = __builtin_amdgcn_mfma_f32_16x16x32_bf16(a[mi], bg[cj], accg[mi][cj], 0, 0, 0);
                accb[mi][cj] = __builtin_amdgcn_mfma_f32_16x16x32_bf16(a[mi], bb[cj], accb[mi][cj], 0, 0, 0);
            }
    }

    unsigned short* mt = m + (size_t)t * N * DD;
#pragma unroll
    for (int mi = 0; mi < 4; mi++)
#pragma unroll
        for (int cj = 0; cj < 2; cj++)
#pragma unroll
            for (int r = 0; r < 4; r++) {
                int row = r0 + mi * 16 + kg * 4 + r;
                if (row < N) {
                    float v = accg[mi][cj][r] * accm[mi][cj][r] + accb[mi][cj][r];
                    v = fmaxf(v, 0.0f);
                    __hip_bfloat16 b = __float2bfloat16(v);
                    mt[(size_t)row * DD + cbase + cj * 16 + lr] =
                        *reinterpret_cast<unsigned short*>(&b);
                }
            }
}

// ---- B: per-bin LDS counting sort + gather + fused LayerNorm ----
__global__ __launch_bounds__(256) void k_sort_agg_ln(const unsigned int* __restrict__ rec,
                                                     const int* __restrict__ binoff,
                                                     const unsigned int* __restrict__ m32,
                                                     const float* __restrict__ lnw,
                                                     const float* __restrict__ lnb,
                                                     float* __restrict__ out, int N) {
    __shared__ int lcnt[128], soff[128], sfill[128], tmp[128];
    __shared__ unsigned int sorted[BCAP];
    const int b = blockIdx.x, tid = threadIdx.x;
    const int s0 = binoff[b];
    int n = binoff[b + 1] - s0;
    if (n > BCAP) n = BCAP;

    if (tid < 128) lcnt[tid] = 0;
    __syncthreads();
    for (int j = tid; j < n; j += 256) atomicAdd(&lcnt[rec[s0 + j] >> 19], 1);
    __syncthreads();
    if (tid < 128) tmp[tid] = lcnt[tid];
    __syncthreads();
    for (int st = 1; st < 128; st <<= 1) {
        int t = 0, a = 0;
        if (tid < 128) {
            t = tmp[tid];
            a = (tid >= st) ? tmp[tid - st] : 0;
        }
        __syncthreads();
        if (tid < 128) tmp[tid] = t + a;
        __syncthreads();
    }
    if (tid < 128) {
        int ex = tmp[tid] - lcnt[tid];
        soff[tid] = ex;
        sfill[tid] = ex;
    }
    __syncthreads();
    for (int j = tid; j < n; j += 256) {
        unsigned int r = rec[s0 + j];
        int p = atomicAdd(&sfill[r >> 19], 1);
        sorted[p] = r & 0x7FFFFu;
    }
    __syncthreads();

    const int wv = tid >> 6, lane = tid & 63;
#pragma unroll 1
    for (int i = 0; i < 32; i++) {
        int d7 = i * 4 + wv;
        int node = b * 128 + d7;
        if (node >= N) continue;  // wave-uniform branch
        int e0 = soff[d7], en = lcnt[d7];
        float a0 = 0.f, a1 = 0.f;
        int e = 0;
        for (; e + 2 <= en; e += 2) {
            unsigned g0 = sorted[e0 + e], g1 = sorted[e0 + e + 1];
            unsigned p0 = m32[(size_t)g0 * 64 + lane];
            unsigned p1 = m32[(size_t)g1 * 64 + lane];
            a0 += bflo(p0) + bflo(p1);
            a1 += bfhi(p0) + bfhi(p1);
        }
        if (e < en) {
            unsigned p0 = m32[(size_t)sorted[e0 + e] * 64 + lane];
            a0 += bflo(p0);
            a1 += bfhi(p0);
        }
        float sum = a0 + a1, ssq = a0 * a0 + a1 * a1;
#pragma unroll
        for (int o = 1; o < 64; o <<= 1) {
            sum += __shfl_xor(sum, o, 64);
            ssq += __shfl_xor(ssq, o, 64);
        }
        float mu = sum * (1.0f / 128.0f);
        float var = ssq * (1.0f / 128.0f) - mu * mu;
        float rstd = rsqrtf(var + LN_EPS);
        int d0 = lane * 2;
        float o0 = (a0 - mu) * rstd * lnw[d0] + lnb[d0];
        float o1 = (a1 - mu) * rstd * lnw[d0 + 1] + lnb[d0 + 1];
        *(float2*)(out + (size_t)node * DD + d0) = make_float2(o0, o1);
    }
}

extern "C" void kernel_launch(void* const* d_in, const int* in_sizes, int n_in,
                              void* d_out, int out_size, void* d_ws, size_t ws_size,
                              hipStream_t stream) {
    const float* feat = (const float*)d_in[0];
    const float* W    = (const float*)d_in[1];
    const float* Wf   = (const float*)d_in[2];
    const float* lnw  = (const float*)d_in[3];
    const float* lnb  = (const float*)d_in[4];
    const int* src    = (const int*)d_in[5];
    const int* dst    = (const int*)d_in[6];
    float* out = (float*)d_out;

    const int N = in_sizes[0] / DD;   // 100000
    const int E = in_sizes[5] / 4;    // 400000
    const int E4 = 4 * E;
    const int NB = (N + 127) >> 7;    // 782 bins
    const int NBLK = (E4 + CHUNK - 1) / CHUNK;  // 391

    size_t off = 0;
    char* ws = (char*)d_ws;
    auto alloc = [&](size_t bytes) -> void* {
        void* p = ws + off;
        off += (bytes + 255) & ~(size_t)255;
        return p;
    };
    unsigned short* m     = (unsigned short*)alloc((size_t)4 * N * DD * 2);  // 102.4 MB
    unsigned short* featb = (unsigned short*)alloc((size_t)N * DD * 2);      // 25.6 MB
    unsigned short* wcat  = (unsigned short*)alloc((size_t)4 * 384 * 128 * 2);
    int* H      = (int*)alloc((size_t)NB * NBLK * 4);                        // 1.2 MB
    int* C      = (int*)alloc((size_t)NB * 4);
    int* binoff = (int*)alloc((size_t)(NB + 1) * 4);
    unsigned int* rec = (unsigned int*)alloc((size_t)E4 * 4);                // 6.4 MB
    if (off > ws_size) return;

    int n8 = N * DD / 8;
    k_pack_feat<<<(n8 + 255) / 256, 256, 0, stream>>>(feat, featb, n8);
    k_pack_w<<<(4 * 384 * 128 + 255) / 256, 256, 0, stream>>>(W, Wf, wcat);
    k_hist2<<<NBLK, 256, 0, stream>>>(dst, H, E4, NBLK, NB);
    k_scanbin<<<(NB * 64 + 255) / 256, 256, 0, stream>>>(H, C, NBLK, NB);
    k_scan<<<1, 1024, 0, stream>>>(C, binoff, NB);
    k_place2<<<NBLK, 256, 0, stream>>>(src, dst, H, binoff, rec, N, E, E4, NBLK, NB);
    dim3 gg((N + 63) / 64, 4);
    k_gemm_film<<<gg, 256, 0, stream>>>(featb, wcat, m, N);
    k_sort_agg_ln<<<NB, 256, 0, stream>>>(rec, binoff, (const unsigned int*)m, lnw, lnb, out, N);
}

// Round 4
// 240.629 us; speedup vs baseline: 4.1789x; 1.2037x over previous
//
#include <hip/hip_runtime.h>
#include <hip/hip_bf16.h>

#define DD 128
#define LN_EPS 1e-5f
#define BCAP 3072      // per-bin record cap (avg 2048, +22 sigma)
#define MAXBIN 1024    // LDS histogram capacity (NBIN = 782 for N=100000)
#define CHUNK 4096     // edges per binning block
#define SPLIT 4        // sub-blocks per bin in the gather (occupancy)

typedef __bf16 bf16x8 __attribute__((ext_vector_type(8)));
typedef float f32x4 __attribute__((ext_vector_type(4)));

__device__ __forceinline__ float bflo(unsigned int u) { return __uint_as_float(u << 16); }
__device__ __forceinline__ float bfhi(unsigned int u) { return __uint_as_float(u & 0xffff0000u); }

// ---- feat fp32 -> bf16 (vectorized, 8 elems/thread) ----
__global__ __launch_bounds__(256) void k_pack_feat(const float* __restrict__ f,
                                                   unsigned short* __restrict__ fb, int n8) {
    int i = blockIdx.x * 256 + threadIdx.x;
    if (i >= n8) return;
    const float4* p = (const float4*)f + (size_t)i * 2;
    float4 v0 = p[0], v1 = p[1];
    float vv[8] = {v0.x, v0.y, v0.z, v0.w, v1.x, v1.y, v1.z, v1.w};
    unsigned short u[8];
#pragma unroll
    for (int j = 0; j < 8; j++) {
        __hip_bfloat16 b = __float2bfloat16(vv[j]);
        u[j] = *reinterpret_cast<unsigned short*>(&b);
    }
    uint4 o;
    o.x = u[0] | ((unsigned)u[1] << 16);
    o.y = u[2] | ((unsigned)u[3] << 16);
    o.z = u[4] | ((unsigned)u[5] << 16);
    o.w = u[6] | ((unsigned)u[7] << 16);
    ((uint4*)fb)[i] = o;
}

// ---- weights -> bf16, column-major concat [t][col 0..383][k 0..127] ----
__global__ __launch_bounds__(256) void k_pack_w(const float* __restrict__ W,
                                                const float* __restrict__ Wf,
                                                unsigned short* __restrict__ wcat) {
    int i = blockIdx.x * 256 + threadIdx.x;
    if (i >= 4 * 384 * 128) return;
    int t = i / (384 * 128);
    int r = i % (384 * 128);
    int c = r / 128, k = r % 128;
    float v = (c < 128) ? W[((size_t)t * 128 + k) * 128 + c]
                        : Wf[((size_t)t * 128 + k) * 256 + (c - 128)];
    __hip_bfloat16 b = __float2bfloat16(v);
    wcat[i] = *reinterpret_cast<unsigned short*>(&b);
}

// ---- P1: per-block LDS histogram -> H[bin*NBLK + blk] ----
__global__ __launch_bounds__(256) void k_hist2(const int* __restrict__ dst,
                                               int* __restrict__ H, int E4, int NBLK, int NBIN) {
    __shared__ int h[MAXBIN];
    const int b = blockIdx.x;
    for (int j = threadIdx.x; j < NBIN; j += 256) h[j] = 0;
    __syncthreads();
    int base = b * CHUNK;
    int end = base + CHUNK < E4 ? base + CHUNK : E4;
    for (int i = base + threadIdx.x; i < end; i += 256) atomicAdd(&h[dst[i] >> 7], 1);
    __syncthreads();
    for (int j = threadIdx.x; j < NBIN; j += 256) H[(size_t)j * NBLK + b] = h[j];
}

// ---- P2: per-bin exclusive scan across blocks (one wave per bin), in place ----
__global__ __launch_bounds__(256) void k_scanbin(int* __restrict__ H, int* __restrict__ C,
                                                 int NBLK, int NBIN) {
    const int wv = (blockIdx.x * 256 + threadIdx.x) >> 6;
    const int lane = threadIdx.x & 63;
    if (wv >= NBIN) return;
    int* row = H + (size_t)wv * NBLK;
    int run = 0;
    for (int base = 0; base < NBLK; base += 64) {
        int idx = base + lane;
        int v = (idx < NBLK) ? row[idx] : 0;
        int s = v;
#pragma unroll
        for (int o = 1; o < 64; o <<= 1) {
            int u = __shfl_up(s, o, 64);
            if (lane >= o) s += u;
        }
        if (idx < NBLK) row[idx] = run + s - v;   // exclusive
        run += __shfl(s, 63, 64);
    }
    if (lane == 0) C[wv] = run;
}

// ---- P3: exclusive scan over NBIN bin totals (one block) ----
__global__ __launch_bounds__(1024) void k_scan(const int* __restrict__ cnt,
                                               int* __restrict__ off, int NB) {
    __shared__ int s[1024];
    int tid = threadIdx.x;
    s[tid] = (tid < NB) ? cnt[tid] : 0;
    __syncthreads();
    for (int st = 1; st < 1024; st <<= 1) {
        int t = s[tid];
        int a = (tid >= st) ? s[tid - st] : 0;
        __syncthreads();
        s[tid] = t + a;
        __syncthreads();
    }
    if (tid < NB) {
        off[tid] = s[tid] - cnt[tid];
        if (tid == NB - 1) off[NB] = s[tid];
    }
}

// ---- P4: place records at deterministic offsets; LDS atomics only ----
__global__ __launch_bounds__(256) void k_place2(const int* __restrict__ src,
                                                const int* __restrict__ dst,
                                                const int* __restrict__ H,
                                                const int* __restrict__ binoff,
                                                unsigned int* __restrict__ rec,
                                                int N, int E, int E4, int NBLK, int NBIN) {
    __shared__ int fill[MAXBIN];
    const int b = blockIdx.x;
    for (int j = threadIdx.x; j < NBIN; j += 256)
        fill[j] = binoff[j] + H[(size_t)j * NBLK + b];
    __syncthreads();
    int base = b * CHUNK;
    int end = base + CHUNK < E4 ? base + CHUNK : E4;
    for (int i = base + threadIdx.x; i < end; i += 256) {
        int d = dst[i];
        int t = i / E;
        unsigned int r = ((unsigned)(d & 127) << 19) | (unsigned)(t * N + src[i]);
        int pos = atomicAdd(&fill[d >> 7], 1);
        rec[pos] = r;
    }
}

// ---- fused GEMM + FiLM (all 4 types per block): m_t = relu(gamma*msg + beta) ----
__global__ __launch_bounds__(256, 2) void k_gemm_film(const unsigned short* __restrict__ featb,
                                                      const unsigned short* __restrict__ wcat,
                                                      unsigned short* __restrict__ m, int N) {
    __shared__ unsigned char smem[64 * 256];  // 64 rows x 128 bf16, XOR-swizzled
    const int r0 = blockIdx.x * 64;
    const int tid = threadIdx.x;

#pragma unroll
    for (int it = 0; it < 4; it++) {
        int c = tid + it * 256;
        int row = c >> 4;
        int kb = (c & 15) * 16;
        int gr = r0 + row;
        uint4 v = {0u, 0u, 0u, 0u};
        if (gr < N) v = *(const uint4*)((const unsigned char*)featb + (size_t)gr * 256 + kb);
        *(uint4*)(smem + row * 256 + (kb ^ ((row & 7) << 4))) = v;
    }
    __syncthreads();

    const int w = tid >> 6, lane = tid & 63;
    const int lr = lane & 15, kg = lane >> 4;
    const int cbase = w * 32;

#pragma unroll 1
    for (int t = 0; t < 4; t++) {
        f32x4 accm[4][2] = {}, accg[4][2] = {}, accb[4][2] = {};
        const unsigned short* wt = wcat + (size_t)t * 384 * 128;

#pragma unroll
        for (int kk = 0; kk < 128; kk += 32) {
            bf16x8 a[4];
#pragma unroll
            for (int mi = 0; mi < 4; mi++) {
                int row = mi * 16 + lr;
                int kb = kk * 2 + kg * 16;
                a[mi] = *(const bf16x8*)(smem + row * 256 + (kb ^ ((row & 7) << 4)));
            }
            const int k0 = kk + kg * 8;
            bf16x8 bm[2], bg[2], bb[2];
#pragma unroll
            for (int cj = 0; cj < 2; cj++) {
                int col = cbase + cj * 16 + lr;
                bm[cj] = *(const bf16x8*)(wt + (size_t)col * 128 + k0);
                bg[cj] = *(const bf16x8*)(wt + (size_t)(128 + col) * 128 + k0);
                bb[cj] = *(const bf16x8*)(wt + (size_t)(256 + col) * 128 + k0);
            }
#pragma unroll
            for (int mi = 0; mi < 4; mi++)
#pragma unroll
                for (int cj = 0; cj < 2; cj++) {
                    accm[mi][cj] = __builtin_amdgcn_mfma_f32_16x16x32_bf16(a[mi], bm[cj], accm[mi][cj], 0, 0, 0);
                    accg[mi][cj] = __builtin_amdgcn_mfma_f32_16x16x32_bf16(a[mi], bg[cj], accg[mi][cj], 0, 0, 0);
                    accb[mi][cj] = __builtin_amdgcn_mfma_f32_16x16x32_bf16(a[mi], bb[cj], accb[mi][cj], 0, 0, 0);
                }
        }

        unsigned short* mt = m + (size_t)t * N * DD;
#pragma unroll
        for (int mi = 0; mi < 4; mi++)
#pragma unroll
            for (int cj = 0; cj < 2; cj++)
#pragma unroll
                for (int r = 0; r < 4; r++) {
                    int row = r0 + mi * 16 + kg * 4 + r;
                    if (row < N) {
                        float v = accg[mi][cj][r] * accm[mi][cj][r] + accb[mi][cj][r];
                        v = fmaxf(v, 0.0f);
                        __hip_bfloat16 b = __float2bfloat16(v);
                        mt[(size_t)row * DD + cbase + cj * 16 + lr] =
                            *reinterpret_cast<unsigned short*>(&b);
                    }
                }
    }
}

// ---- B: per-bin LDS counting sort + gather + fused LayerNorm ----
// SPLIT sub-blocks per bin: each re-sorts (cheap) and aggregates 128/SPLIT nodes.
__global__ __launch_bounds__(256) void k_sort_agg_ln(const unsigned int* __restrict__ rec,
                                                     const int* __restrict__ binoff,
                                                     const unsigned int* __restrict__ m32,
                                                     const float* __restrict__ lnw,
                                                     const float* __restrict__ lnb,
                                                     float* __restrict__ out, int N) {
    __shared__ int lcnt[128], soff[128], sfill[128], tmp[128];
    __shared__ unsigned int sorted[BCAP];
    const int b = blockIdx.x / SPLIT, sub = blockIdx.x % SPLIT;
    const int tid = threadIdx.x;
    const int s0 = binoff[b];
    int n = binoff[b + 1] - s0;
    if (n > BCAP) n = BCAP;

    if (tid < 128) lcnt[tid] = 0;
    __syncthreads();
    for (int j = tid; j < n; j += 256) atomicAdd(&lcnt[rec[s0 + j] >> 19], 1);
    __syncthreads();
    if (tid < 128) tmp[tid] = lcnt[tid];
    __syncthreads();
    for (int st = 1; st < 128; st <<= 1) {
        int t = 0, a = 0;
        if (tid < 128) {
            t = tmp[tid];
            a = (tid >= st) ? tmp[tid - st] : 0;
        }
        __syncthreads();
        if (tid < 128) tmp[tid] = t + a;
        __syncthreads();
    }
    if (tid < 128) {
        int ex = tmp[tid] - lcnt[tid];
        soff[tid] = ex;
        sfill[tid] = ex;
    }
    __syncthreads();
    for (int j = tid; j < n; j += 256) {
        unsigned int r = rec[s0 + j];
        int p = atomicAdd(&sfill[r >> 19], 1);
        sorted[p] = r & 0x7FFFFu;
    }
    __syncthreads();

    const int wv = tid >> 6, lane = tid & 63;
#pragma unroll 1
    for (int i = 0; i < 128 / SPLIT / 4; i++) {
        int d7 = sub * (128 / SPLIT) + i * 4 + wv;
        int node = b * 128 + d7;
        if (node >= N) continue;  // wave-uniform branch
        int e0 = soff[d7], en = lcnt[d7];
        float a0 = 0.f, a1 = 0.f;
        int e = 0;
        for (; e + 4 <= en; e += 4) {
            unsigned g0 = sorted[e0 + e], g1 = sorted[e0 + e + 1];
            unsigned g2 = sorted[e0 + e + 2], g3 = sorted[e0 + e + 3];
            unsigned p0 = m32[(size_t)g0 * 64 + lane];
            unsigned p1 = m32[(size_t)g1 * 64 + lane];
            unsigned p2 = m32[(size_t)g2 * 64 + lane];
            unsigned p3 = m32[(size_t)g3 * 64 + lane];
            a0 += bflo(p0) + bflo(p1) + bflo(p2) + bflo(p3);
            a1 += bfhi(p0) + bfhi(p1) + bfhi(p2) + bfhi(p3);
        }
        for (; e < en; e++) {
            unsigned p0 = m32[(size_t)sorted[e0 + e] * 64 + lane];
            a0 += bflo(p0);
            a1 += bfhi(p0);
        }
        float sum = a0 + a1, ssq = a0 * a0 + a1 * a1;
#pragma unroll
        for (int o = 1; o < 64; o <<= 1) {
            sum += __shfl_xor(sum, o, 64);
            ssq += __shfl_xor(ssq, o, 64);
        }
        float mu = sum * (1.0f / 128.0f);
        float var = ssq * (1.0f / 128.0f) - mu * mu;
        float rstd = rsqrtf(var + LN_EPS);
        int d0 = lane * 2;
        float o0 = (a0 - mu) * rstd * lnw[d0] + lnb[d0];
        float o1 = (a1 - mu) * rstd * lnw[d0 + 1] + lnb[d0 + 1];
        *(float2*)(out + (size_t)node * DD + d0) = make_float2(o0, o1);
    }
}

extern "C" void kernel_launch(void* const* d_in, const int* in_sizes, int n_in,
                              void* d_out, int out_size, void* d_ws, size_t ws_size,
                              hipStream_t stream) {
    const float* feat = (const float*)d_in[0];
    const float* W    = (const float*)d_in[1];
    const float* Wf   = (const float*)d_in[2];
    const float* lnw  = (const float*)d_in[3];
    const float* lnb  = (const float*)d_in[4];
    const int* src    = (const int*)d_in[5];
    const int* dst    = (const int*)d_in[6];
    float* out = (float*)d_out;

    const int N = in_sizes[0] / DD;   // 100000
    const int E = in_sizes[5] / 4;    // 400000
    const int E4 = 4 * E;
    const int NB = (N + 127) >> 7;    // 782 bins
    const int NBLK = (E4 + CHUNK - 1) / CHUNK;  // 391

    size_t off = 0;
    char* ws = (char*)d_ws;
    auto alloc = [&](size_t bytes) -> void* {
        void* p = ws + off;
        off += (bytes + 255) & ~(size_t)255;
        return p;
    };
    unsigned short* m     = (unsigned short*)alloc((size_t)4 * N * DD * 2);  // 102.4 MB
    unsigned short* featb = (unsigned short*)alloc((size_t)N * DD * 2);      // 25.6 MB
    unsigned short* wcat  = (unsigned short*)alloc((size_t)4 * 384 * 128 * 2);
    int* H      = (int*)alloc((size_t)NB * NBLK * 4);                        // 1.2 MB
    int* C      = (int*)alloc((size_t)NB * 4);
    int* binoff = (int*)alloc((size_t)(NB + 1) * 4);
    unsigned int* rec = (unsigned int*)alloc((size_t)E4 * 4);                // 6.4 MB
    if (off > ws_size) return;

    int n8 = N * DD / 8;
    k_pack_feat<<<(n8 + 255) / 256, 256, 0, stream>>>(feat, featb, n8);
    k_pack_w<<<(4 * 384 * 128 + 255) / 256, 256, 0, stream>>>(W, Wf, wcat);
    k_hist2<<<NBLK, 256, 0, stream>>>(dst, H, E4, NBLK, NB);
    k_scanbin<<<(NB * 64 + 255) / 256, 256, 0, stream>>>(H, C, NBLK, NB);
    k_scan<<<1, 1024, 0, stream>>>(C, binoff, NB);
    k_place2<<<NBLK, 256, 0, stream>>>(src, dst, H, binoff, rec, N, E, E4, NBLK, NB);
    k_gemm_film<<<(N + 63) / 64, 256, 0, stream>>>(featb, wcat, m, N);
    k_sort_agg_ln<<<NB * SPLIT, 256, 0, stream>>>(rec, binoff, (const unsigned int*)m, lnw, lnb, out, N);
}

// Round 5
// 182.992 us; speedup vs baseline: 5.4951x; 1.3150x over previous
//
#include <hip/hip_runtime.h>
#include <hip/hip_bf16.h>

#define DD 128
#define LN_EPS 1e-5f
#define BCAP 3072      // per-bin record cap (avg 2048, +22 sigma)
#define MAXBIN 1024    // LDS histogram capacity (NBIN = 782 for N=100000)
#define CHUNK 4096     // edges per binning block
#define SPLIT 4        // sub-blocks per bin in the gather (occupancy)

typedef __bf16 bf16x8 __attribute__((ext_vector_type(8)));
typedef float f32x4 __attribute__((ext_vector_type(4)));

__device__ __forceinline__ float bflo(unsigned int u) { return __uint_as_float(u << 16); }
__device__ __forceinline__ float bfhi(unsigned int u) { return __uint_as_float(u & 0xffff0000u); }

__device__ __forceinline__ void gload_lds16(const void* g, void* lds) {
    __builtin_amdgcn_global_load_lds(
        (const __attribute__((address_space(1))) unsigned int*)g,
        (__attribute__((address_space(3))) unsigned int*)lds, 16, 0, 0);
}

// ---- feat fp32 -> bf16 (vectorized, 8 elems/thread) ----
__global__ __launch_bounds__(256) void k_pack_feat(const float* __restrict__ f,
                                                   unsigned short* __restrict__ fb, int n8) {
    int i = blockIdx.x * 256 + threadIdx.x;
    if (i >= n8) return;
    const float4* p = (const float4*)f + (size_t)i * 2;
    float4 v0 = p[0], v1 = p[1];
    float vv[8] = {v0.x, v0.y, v0.z, v0.w, v1.x, v1.y, v1.z, v1.w};
    unsigned short u[8];
#pragma unroll
    for (int j = 0; j < 8; j++) {
        __hip_bfloat16 b = __float2bfloat16(vv[j]);
        u[j] = *reinterpret_cast<unsigned short*>(&b);
    }
    uint4 o;
    o.x = u[0] | ((unsigned)u[1] << 16);
    o.y = u[2] | ((unsigned)u[3] << 16);
    o.z = u[4] | ((unsigned)u[5] << 16);
    o.w = u[6] | ((unsigned)u[7] << 16);
    ((uint4*)fb)[i] = o;
}

// ---- weights -> bf16, column-major concat [t][col 0..383][k 0..127] ----
__global__ __launch_bounds__(256) void k_pack_w(const float* __restrict__ W,
                                                const float* __restrict__ Wf,
                                                unsigned short* __restrict__ wcat) {
    int i = blockIdx.x * 256 + threadIdx.x;
    if (i >= 4 * 384 * 128) return;
    int t = i / (384 * 128);
    int r = i % (384 * 128);
    int c = r / 128, k = r % 128;
    float v = (c < 128) ? W[((size_t)t * 128 + k) * 128 + c]
                        : Wf[((size_t)t * 128 + k) * 256 + (c - 128)];
    __hip_bfloat16 b = __float2bfloat16(v);
    wcat[i] = *reinterpret_cast<unsigned short*>(&b);
}

// ---- P1: per-block LDS histogram -> H[bin*NBLK + blk] ----
__global__ __launch_bounds__(256) void k_hist2(const int* __restrict__ dst,
                                               int* __restrict__ H, int E4, int NBLK, int NBIN) {
    __shared__ int h[MAXBIN];
    const int b = blockIdx.x;
    for (int j = threadIdx.x; j < NBIN; j += 256) h[j] = 0;
    __syncthreads();
    int base = b * CHUNK;
    int end = base + CHUNK < E4 ? base + CHUNK : E4;
    for (int i = base + threadIdx.x; i < end; i += 256) atomicAdd(&h[dst[i] >> 7], 1);
    __syncthreads();
    for (int j = threadIdx.x; j < NBIN; j += 256) H[(size_t)j * NBLK + b] = h[j];
}

// ---- P2: per-bin exclusive scan across blocks (one wave per bin), in place ----
__global__ __launch_bounds__(256) void k_scanbin(int* __restrict__ H, int* __restrict__ C,
                                                 int NBLK, int NBIN) {
    const int wv = (blockIdx.x * 256 + threadIdx.x) >> 6;
    const int lane = threadIdx.x & 63;
    if (wv >= NBIN) return;
    int* row = H + (size_t)wv * NBLK;
    int run = 0;
    for (int base = 0; base < NBLK; base += 64) {
        int idx = base + lane;
        int v = (idx < NBLK) ? row[idx] : 0;
        int s = v;
#pragma unroll
        for (int o = 1; o < 64; o <<= 1) {
            int u = __shfl_up(s, o, 64);
            if (lane >= o) s += u;
        }
        if (idx < NBLK) row[idx] = run + s - v;   // exclusive
        run += __shfl(s, 63, 64);
    }
    if (lane == 0) C[wv] = run;
}

// ---- P3: exclusive scan over NBIN bin totals (one block) ----
__global__ __launch_bounds__(1024) void k_scan(const int* __restrict__ cnt,
                                               int* __restrict__ off, int NB) {
    __shared__ int s[1024];
    int tid = threadIdx.x;
    s[tid] = (tid < NB) ? cnt[tid] : 0;
    __syncthreads();
    for (int st = 1; st < 1024; st <<= 1) {
        int t = s[tid];
        int a = (tid >= st) ? s[tid - st] : 0;
        __syncthreads();
        s[tid] = t + a;
        __syncthreads();
    }
    if (tid < NB) {
        off[tid] = s[tid] - cnt[tid];
        if (tid == NB - 1) off[NB] = s[tid];
    }
}

// ---- P4: place records at deterministic offsets; LDS atomics only ----
__global__ __launch_bounds__(256) void k_place2(const int* __restrict__ src,
                                                const int* __restrict__ dst,
                                                const int* __restrict__ H,
                                                const int* __restrict__ binoff,
                                                unsigned int* __restrict__ rec,
                                                int N, int E, int E4, int NBLK, int NBIN) {
    __shared__ int fill[MAXBIN];
    const int b = blockIdx.x;
    for (int j = threadIdx.x; j < NBIN; j += 256)
        fill[j] = binoff[j] + H[(size_t)j * NBLK + b];
    __syncthreads();
    int base = b * CHUNK;
    int end = base + CHUNK < E4 ? base + CHUNK : E4;
    for (int i = base + threadIdx.x; i < end; i += 256) {
        int d = dst[i];
        int t = i / E;
        unsigned int r = ((unsigned)(d & 127) << 19) | (unsigned)(t * N + src[i]);
        int pos = atomicAdd(&fill[d >> 7], 1);
        rec[pos] = r;
    }
}

// ---- fused GEMM + FiLM, B-stationary: m_t = relu(gamma*msg + beta) ----
// grid = (GX, 4): t = blockIdx.y; each wave preloads all its B frags (24 x bf16x8)
// and grid-strides over 64-row tiles. A staged via global_load_lds, double-buffered.
__global__ __launch_bounds__(256, 2) void k_gemm_film(const unsigned short* __restrict__ featb,
                                                      const unsigned short* __restrict__ wcat,
                                                      unsigned short* __restrict__ m, int N,
                                                      int NT) {
    __shared__ unsigned char smem[2 * 16384];  // double-buffered 64x128 bf16, XOR-swizzled
    const int t = blockIdx.y;
    const int tid = threadIdx.x;
    const int w = tid >> 6, lane = tid & 63;
    const int lr = lane & 15, kg = lane >> 4;
    const int cbase = w * 32;

    // ---- preload B: [kkI][mat][cj], col-major wcat[t][col][k] ----
    const unsigned short* wt = wcat + (size_t)t * 384 * 128;
    bf16x8 B[4][3][2];
#pragma unroll
    for (int kkI = 0; kkI < 4; kkI++)
#pragma unroll
        for (int mat = 0; mat < 3; mat++)
#pragma unroll
            for (int cj = 0; cj < 2; cj++) {
                int col = mat * 128 + cbase + cj * 16 + lr;
                B[kkI][mat][cj] = *(const bf16x8*)(wt + (size_t)col * 128 + kkI * 32 + kg * 8);
            }

    // ---- stage helper: tile (64 rows at r0) -> smem[buf], swizzled, async ----
    auto stage = [&](int buf, int r0) {
#pragma unroll
        for (int it = 0; it < 4; it++) {
            int row = it * 16 + w * 4 + (lane >> 4);
            int gr = r0 + row;
            if (gr >= N) gr = N - 1;
            int x = ((lane & 15) * 16) ^ ((row & 7) << 4);
            const unsigned char* g = (const unsigned char*)featb + (size_t)gr * 256 + x;
            gload_lds16(g, smem + buf * 16384 + it * 4096 + w * 1024);
        }
    };

    unsigned short* mt = m + (size_t)t * N * DD;
    int buf = 0;
    int tile = blockIdx.x;
    if (tile < NT) stage(0, tile * 64);

    for (; tile < NT; tile += gridDim.x) {
        __syncthreads();  // drains vmcnt: smem[buf] ready; prev readers done
        int nxt = tile + gridDim.x;
        if (nxt < NT) stage(buf ^ 1, nxt * 64);

        const unsigned char* sm = smem + buf * 16384;
        f32x4 acc[4][3][2] = {};
#pragma unroll
        for (int kkI = 0; kkI < 4; kkI++) {
            bf16x8 a[4];
#pragma unroll
            for (int mi = 0; mi < 4; mi++) {
                int row = mi * 16 + lr;
                int kb = kkI * 64 + kg * 16;
                a[mi] = *(const bf16x8*)(sm + row * 256 + (kb ^ ((row & 7) << 4)));
            }
#pragma unroll
            for (int mi = 0; mi < 4; mi++)
#pragma unroll
                for (int mat = 0; mat < 3; mat++)
#pragma unroll
                    for (int cj = 0; cj < 2; cj++)
                        acc[mi][mat][cj] = __builtin_amdgcn_mfma_f32_16x16x32_bf16(
                            a[mi], B[kkI][mat][cj], acc[mi][mat][cj], 0, 0, 0);
        }

        const int r0 = tile * 64;
#pragma unroll
        for (int mi = 0; mi < 4; mi++)
#pragma unroll
            for (int cj = 0; cj < 2; cj++)
#pragma unroll
                for (int r = 0; r < 4; r++) {
                    int row = r0 + mi * 16 + kg * 4 + r;
                    if (row < N) {
                        float v = acc[mi][1][cj][r] * acc[mi][0][cj][r] + acc[mi][2][cj][r];
                        v = fmaxf(v, 0.0f);
                        __hip_bfloat16 b = __float2bfloat16(v);
                        mt[(size_t)row * DD + cbase + cj * 16 + lr] =
                            *reinterpret_cast<unsigned short*>(&b);
                    }
                }
        buf ^= 1;
    }
}

// ---- B: per-bin LDS counting sort + gather + fused LayerNorm ----
// SPLIT sub-blocks per bin: each re-sorts (cheap) and aggregates 128/SPLIT nodes.
__global__ __launch_bounds__(256) void k_sort_agg_ln(const unsigned int* __restrict__ rec,
                                                     const int* __restrict__ binoff,
                                                     const unsigned int* __restrict__ m32,
                                                     const float* __restrict__ lnw,
                                                     const float* __restrict__ lnb,
                                                     float* __restrict__ out, int N) {
    __shared__ int lcnt[128], soff[128], sfill[128], tmp[128];
    __shared__ unsigned int sorted[BCAP];
    const int b = blockIdx.x / SPLIT, sub = blockIdx.x % SPLIT;
    const int tid = threadIdx.x;
    const int s0 = binoff[b];
    int n = binoff[b + 1] - s0;
    if (n > BCAP) n = BCAP;

    if (tid < 128) lcnt[tid] = 0;
    __syncthreads();
    for (int j = tid; j < n; j += 256) atomicAdd(&lcnt[rec[s0 + j] >> 19], 1);
    __syncthreads();
    if (tid < 128) tmp[tid] = lcnt[tid];
    __syncthreads();
    for (int st = 1; st < 128; st <<= 1) {
        int t = 0, a = 0;
        if (tid < 128) {
            t = tmp[tid];
            a = (tid >= st) ? tmp[tid - st] : 0;
        }
        __syncthreads();
        if (tid < 128) tmp[tid] = t + a;
        __syncthreads();
    }
    if (tid < 128) {
        int ex = tmp[tid] - lcnt[tid];
        soff[tid] = ex;
        sfill[tid] = ex;
    }
    __syncthreads();
    for (int j = tid; j < n; j += 256) {
        unsigned int r = rec[s0 + j];
        int p = atomicAdd(&sfill[r >> 19], 1);
        sorted[p] = r & 0x7FFFFu;
    }
    __syncthreads();

    const int wv = tid >> 6, lane = tid & 63;
#pragma unroll 1
    for (int i = 0; i < 128 / SPLIT / 4; i++) {
        int d7 = sub * (128 / SPLIT) + i * 4 + wv;
        int node = b * 128 + d7;
        if (node >= N) continue;  // wave-uniform branch
        int e0 = soff[d7], en = lcnt[d7];
        float a0 = 0.f, a1 = 0.f;
        int e = 0;
        for (; e + 4 <= en; e += 4) {
            unsigned g0 = sorted[e0 + e], g1 = sorted[e0 + e + 1];
            unsigned g2 = sorted[e0 + e + 2], g3 = sorted[e0 + e + 3];
            unsigned p0 = m32[(size_t)g0 * 64 + lane];
            unsigned p1 = m32[(size_t)g1 * 64 + lane];
            unsigned p2 = m32[(size_t)g2 * 64 + lane];
            unsigned p3 = m32[(size_t)g3 * 64 + lane];
            a0 += bflo(p0) + bflo(p1) + bflo(p2) + bflo(p3);
            a1 += bfhi(p0) + bfhi(p1) + bfhi(p2) + bfhi(p3);
        }
        for (; e < en; e++) {
            unsigned p0 = m32[(size_t)sorted[e0 + e] * 64 + lane];
            a0 += bflo(p0);
            a1 += bfhi(p0);
        }
        float sum = a0 + a1, ssq = a0 * a0 + a1 * a1;
#pragma unroll
        for (int o = 1; o < 64; o <<= 1) {
            sum += __shfl_xor(sum, o, 64);
            ssq += __shfl_xor(ssq, o, 64);
        }
        float mu = sum * (1.0f / 128.0f);
        float var = ssq * (1.0f / 128.0f) - mu * mu;
        float rstd = rsqrtf(var + LN_EPS);
        int d0 = lane * 2;
        float o0 = (a0 - mu) * rstd * lnw[d0] + lnb[d0];
        float o1 = (a1 - mu) * rstd * lnw[d0 + 1] + lnb[d0 + 1];
        *(float2*)(out + (size_t)node * DD + d0) = make_float2(o0, o1);
    }
}

extern "C" void kernel_launch(void* const* d_in, const int* in_sizes, int n_in,
                              void* d_out, int out_size, void* d_ws, size_t ws_size,
                              hipStream_t stream) {
    const float* feat = (const float*)d_in[0];
    const float* W    = (const float*)d_in[1];
    const float* Wf   = (const float*)d_in[2];
    const float* lnw  = (const float*)d_in[3];
    const float* lnb  = (const float*)d_in[4];
    const int* src    = (const int*)d_in[5];
    const int* dst    = (const int*)d_in[6];
    float* out = (float*)d_out;

    const int N = in_sizes[0] / DD;   // 100000
    const int E = in_sizes[5] / 4;    // 400000
    const int E4 = 4 * E;
    const int NB = (N + 127) >> 7;    // 782 bins
    const int NBLK = (E4 + CHUNK - 1) / CHUNK;  // 391
    const int NT = (N + 63) / 64;     // 1563 row tiles

    size_t off = 0;
    char* ws = (char*)d_ws;
    auto alloc = [&](size_t bytes) -> void* {
        void* p = ws + off;
        off += (bytes + 255) & ~(size_t)255;
        return p;
    };
    unsigned short* m     = (unsigned short*)alloc((size_t)4 * N * DD * 2);  // 102.4 MB
    unsigned short* featb = (unsigned short*)alloc((size_t)N * DD * 2);      // 25.6 MB
    unsigned short* wcat  = (unsigned short*)alloc((size_t)4 * 384 * 128 * 2);
    int* H      = (int*)alloc((size_t)NB * NBLK * 4);                        // 1.2 MB
    int* C      = (int*)alloc((size_t)NB * 4);
    int* binoff = (int*)alloc((size_t)(NB + 1) * 4);
    unsigned int* rec = (unsigned int*)alloc((size_t)E4 * 4);                // 6.4 MB
    if (off > ws_size) return;

    int n8 = N * DD / 8;
    k_pack_feat<<<(n8 + 255) / 256, 256, 0, stream>>>(feat, featb, n8);
    k_pack_w<<<(4 * 384 * 128 + 255) / 256, 256, 0, stream>>>(W, Wf, wcat);
    k_hist2<<<NBLK, 256, 0, stream>>>(dst, H, E4, NBLK, NB);
    k_scanbin<<<(NB * 64 + 255) / 256, 256, 0, stream>>>(H, C, NBLK, NB);
    k_scan<<<1, 1024, 0, stream>>>(C, binoff, NB);
    k_place2<<<NBLK, 256, 0, stream>>>(src, dst, H, binoff, rec, N, E, E4, NBLK, NB);
    dim3 gg(128, 4);
    k_gemm_film<<<gg, 256, 0, stream>>>(featb, wcat, m, N, NT);
    k_sort_agg_ln<<<NB * SPLIT, 256, 0, stream>>>(rec, binoff, (const unsigned int*)m, lnw, lnb, out, N);
}

// Round 6
// 176.472 us; speedup vs baseline: 5.6982x; 1.0369x over previous
//
#include <hip/hip_runtime.h>
#include <hip/hip_bf16.h>

#define DD 128
#define LN_EPS 1e-5f
#define BCAP 3072      // per-bin record cap (avg 2048, +22 sigma)
#define MAXBIN 1024    // LDS histogram capacity (NBIN = 782 for N=100000)
#define CHUNK 4096     // edges per binning block

typedef __bf16 bf16x8 __attribute__((ext_vector_type(8)));
typedef float f32x4 __attribute__((ext_vector_type(4)));

__device__ __forceinline__ float bflo(unsigned int u) { return __uint_as_float(u << 16); }
__device__ __forceinline__ float bfhi(unsigned int u) { return __uint_as_float(u & 0xffff0000u); }

__device__ __forceinline__ void gload_lds16(const void* g, void* lds) {
    __builtin_amdgcn_global_load_lds(
        (const __attribute__((address_space(1))) unsigned int*)g,
        (__attribute__((address_space(3))) unsigned int*)lds, 16, 0, 0);
}

// ---- feat fp32 -> bf16 (vectorized, 8 elems/thread) ----
__global__ __launch_bounds__(256) void k_pack_feat(const float* __restrict__ f,
                                                   unsigned short* __restrict__ fb, int n8) {
    int i = blockIdx.x * 256 + threadIdx.x;
    if (i >= n8) return;
    const float4* p = (const float4*)f + (size_t)i * 2;
    float4 v0 = p[0], v1 = p[1];
    float vv[8] = {v0.x, v0.y, v0.z, v0.w, v1.x, v1.y, v1.z, v1.w};
    unsigned short u[8];
#pragma unroll
    for (int j = 0; j < 8; j++) {
        __hip_bfloat16 b = __float2bfloat16(vv[j]);
        u[j] = *reinterpret_cast<unsigned short*>(&b);
    }
    uint4 o;
    o.x = u[0] | ((unsigned)u[1] << 16);
    o.y = u[2] | ((unsigned)u[3] << 16);
    o.z = u[4] | ((unsigned)u[5] << 16);
    o.w = u[6] | ((unsigned)u[7] << 16);
    ((uint4*)fb)[i] = o;
}

// ---- weights -> bf16, column-major concat [t][col 0..383][k 0..127] ----
__global__ __launch_bounds__(256) void k_pack_w(const float* __restrict__ W,
                                                const float* __restrict__ Wf,
                                                unsigned short* __restrict__ wcat) {
    int i = blockIdx.x * 256 + threadIdx.x;
    if (i >= 4 * 384 * 128) return;
    int t = i / (384 * 128);
    int r = i % (384 * 128);
    int c = r / 128, k = r % 128;
    float v = (c < 128) ? W[((size_t)t * 128 + k) * 128 + c]
                        : Wf[((size_t)t * 128 + k) * 256 + (c - 128)];
    __hip_bfloat16 b = __float2bfloat16(v);
    wcat[i] = *reinterpret_cast<unsigned short*>(&b);
}

// ---- P1: per-block LDS histogram -> H[bin*NBLK + blk] ----
__global__ __launch_bounds__(256) void k_hist2(const int* __restrict__ dst,
                                               int* __restrict__ H, int E4, int NBLK, int NBIN) {
    __shared__ int h[MAXBIN];
    const int b = blockIdx.x;
    for (int j = threadIdx.x; j < NBIN; j += 256) h[j] = 0;
    __syncthreads();
    int base = b * CHUNK;
    int end = base + CHUNK < E4 ? base + CHUNK : E4;
    for (int i = base + threadIdx.x; i < end; i += 256) atomicAdd(&h[dst[i] >> 7], 1);
    __syncthreads();
    for (int j = threadIdx.x; j < NBIN; j += 256) H[(size_t)j * NBLK + b] = h[j];
}

// ---- P2: per-bin exclusive scan across blocks (one wave per bin), in place ----
__global__ __launch_bounds__(256) void k_scanbin(int* __restrict__ H, int* __restrict__ C,
                                                 int NBLK, int NBIN) {
    const int wv = (blockIdx.x * 256 + threadIdx.x) >> 6;
    const int lane = threadIdx.x & 63;
    if (wv >= NBIN) return;
    int* row = H + (size_t)wv * NBLK;
    int run = 0;
    for (int base = 0; base < NBLK; base += 64) {
        int idx = base + lane;
        int v = (idx < NBLK) ? row[idx] : 0;
        int s = v;
#pragma unroll
        for (int o = 1; o < 64; o <<= 1) {
            int u = __shfl_up(s, o, 64);
            if (lane >= o) s += u;
        }
        if (idx < NBLK) row[idx] = run + s - v;   // exclusive
        run += __shfl(s, 63, 64);
    }
    if (lane == 0) C[wv] = run;
}

// ---- P3: exclusive scan over NBIN bin totals (one block) ----
__global__ __launch_bounds__(1024) void k_scan(const int* __restrict__ cnt,
                                               int* __restrict__ off, int NB) {
    __shared__ int s[1024];
    int tid = threadIdx.x;
    s[tid] = (tid < NB) ? cnt[tid] : 0;
    __syncthreads();
    for (int st = 1; st < 1024; st <<= 1) {
        int t = s[tid];
        int a = (tid >= st) ? s[tid - st] : 0;
        __syncthreads();
        s[tid] = t + a;
        __syncthreads();
    }
    if (tid < NB) {
        off[tid] = s[tid] - cnt[tid];
        if (tid == NB - 1) off[NB] = s[tid];
    }
}

// ---- P4: place records at deterministic offsets; LDS atomics only ----
__global__ __launch_bounds__(256) void k_place2(const int* __restrict__ src,
                                                const int* __restrict__ dst,
                                                const int* __restrict__ H,
                                                const int* __restrict__ binoff,
                                                unsigned int* __restrict__ rec,
                                                int N, int E, int E4, int NBLK, int NBIN) {
    __shared__ int fill[MAXBIN];
    const int b = blockIdx.x;
    for (int j = threadIdx.x; j < NBIN; j += 256)
        fill[j] = binoff[j] + H[(size_t)j * NBLK + b];
    __syncthreads();
    int base = b * CHUNK;
    int end = base + CHUNK < E4 ? base + CHUNK : E4;
    for (int i = base + threadIdx.x; i < end; i += 256) {
        int d = dst[i];
        int t = i / E;
        unsigned int r = ((unsigned)(d & 127) << 19) | (unsigned)(t * N + src[i]);
        int pos = atomicAdd(&fill[d >> 7], 1);
        rec[pos] = r;
    }
}

// ---- P5: per-bin LDS counting sort -> global CSR (sorted edges + start/deg) ----
__global__ __launch_bounds__(256) void k_sortout(const unsigned int* __restrict__ rec,
                                                 const int* __restrict__ binoff,
                                                 unsigned int* __restrict__ sortedg,
                                                 int* __restrict__ nodestart,
                                                 int* __restrict__ nodedeg, int N) {
    __shared__ int lcnt[128], soff[128], sfill[128], tmp[128];
    __shared__ unsigned int sorted[BCAP];
    const int b = blockIdx.x, tid = threadIdx.x;
    const int s0 = binoff[b];
    int n = binoff[b + 1] - s0;
    if (n > BCAP) n = BCAP;

    if (tid < 128) lcnt[tid] = 0;
    __syncthreads();
    for (int j = tid; j < n; j += 256) atomicAdd(&lcnt[rec[s0 + j] >> 19], 1);
    __syncthreads();
    if (tid < 128) tmp[tid] = lcnt[tid];
    __syncthreads();
    for (int st = 1; st < 128; st <<= 1) {
        int t = 0, a = 0;
        if (tid < 128) {
            t = tmp[tid];
            a = (tid >= st) ? tmp[tid - st] : 0;
        }
        __syncthreads();
        if (tid < 128) tmp[tid] = t + a;
        __syncthreads();
    }
    if (tid < 128) {
        int ex = tmp[tid] - lcnt[tid];
        soff[tid] = ex;
        sfill[tid] = ex;
    }
    __syncthreads();
    for (int j = tid; j < n; j += 256) {
        unsigned int r = rec[s0 + j];
        int p = atomicAdd(&sfill[r >> 19], 1);
        sorted[p] = r & 0x7FFFFu;
    }
    __syncthreads();
    for (int j = tid; j < n; j += 256) sortedg[s0 + j] = sorted[j];
    if (tid < 128) {
        int node = b * 128 + tid;
        if (node < N) {
            nodestart[node] = s0 + soff[tid];
            nodedeg[node] = lcnt[tid];
        }
    }
}

// ---- fused GEMM + FiLM, B-stationary: m_t = relu(gamma*msg + beta) ----
__global__ __launch_bounds__(256, 2) void k_gemm_film(const unsigned short* __restrict__ featb,
                                                      const unsigned short* __restrict__ wcat,
                                                      unsigned short* __restrict__ m, int N,
                                                      int NT) {
    __shared__ unsigned char smem[2 * 16384];  // double-buffered 64x128 bf16, XOR-swizzled
    const int t = blockIdx.y;
    const int tid = threadIdx.x;
    const int w = tid >> 6, lane = tid & 63;
    const int lr = lane & 15, kg = lane >> 4;
    const int cbase = w * 32;

    const unsigned short* wt = wcat + (size_t)t * 384 * 128;
    bf16x8 B[4][3][2];
#pragma unroll
    for (int kkI = 0; kkI < 4; kkI++)
#pragma unroll
        for (int mat = 0; mat < 3; mat++)
#pragma unroll
            for (int cj = 0; cj < 2; cj++) {
                int col = mat * 128 + cbase + cj * 16 + lr;
                B[kkI][mat][cj] = *(const bf16x8*)(wt + (size_t)col * 128 + kkI * 32 + kg * 8);
            }

    auto stage = [&](int buf, int r0) {
#pragma unroll
        for (int it = 0; it < 4; it++) {
            int row = it * 16 + w * 4 + (lane >> 4);
            int gr = r0 + row;
            if (gr >= N) gr = N - 1;
            int x = ((lane & 15) * 16) ^ ((row & 7) << 4);
            const unsigned char* g = (const unsigned char*)featb + (size_t)gr * 256 + x;
            gload_lds16(g, smem + buf * 16384 + it * 4096 + w * 1024);
        }
    };

    unsigned short* mt = m + (size_t)t * N * DD;
    int buf = 0;
    int tile = blockIdx.x;
    if (tile < NT) stage(0, tile * 64);

    for (; tile < NT; tile += gridDim.x) {
        __syncthreads();
        int nxt = tile + gridDim.x;
        if (nxt < NT) stage(buf ^ 1, nxt * 64);

        const unsigned char* sm = smem + buf * 16384;
        f32x4 acc[4][3][2] = {};
#pragma unroll
        for (int kkI = 0; kkI < 4; kkI++) {
            bf16x8 a[4];
#pragma unroll
            for (int mi = 0; mi < 4; mi++) {
                int row = mi * 16 + lr;
                int kb = kkI * 64 + kg * 16;
                a[mi] = *(const bf16x8*)(sm + row * 256 + (kb ^ ((row & 7) << 4)));
            }
#pragma unroll
            for (int mi = 0; mi < 4; mi++)
#pragma unroll
                for (int mat = 0; mat < 3; mat++)
#pragma unroll
                    for (int cj = 0; cj < 2; cj++)
                        acc[mi][mat][cj] = __builtin_amdgcn_mfma_f32_16x16x32_bf16(
                            a[mi], B[kkI][mat][cj], acc[mi][mat][cj], 0, 0, 0);
        }

        const int r0 = tile * 64;
#pragma unroll
        for (int mi = 0; mi < 4; mi++)
#pragma unroll
            for (int cj = 0; cj < 2; cj++)
#pragma unroll
                for (int r = 0; r < 4; r++) {
                    int row = r0 + mi * 16 + kg * 4 + r;
                    if (row < N) {
                        float v = acc[mi][1][cj][r] * acc[mi][0][cj][r] + acc[mi][2][cj][r];
                        v = fmaxf(v, 0.0f);
                        __hip_bfloat16 b = __float2bfloat16(v);
                        mt[(size_t)row * DD + cbase + cj * 16 + lr] =
                            *reinterpret_cast<unsigned short*>(&b);
                    }
                }
        buf ^= 1;
    }
}

// ---- B: CSR gather + fused LayerNorm. 1 wave/node, half-wave = 1 row, uint2/lane ----
__global__ __launch_bounds__(256) void k_agg_ln(const unsigned int* __restrict__ sortedg,
                                                const int* __restrict__ nodestart,
                                                const int* __restrict__ nodedeg,
                                                const uint2* __restrict__ m2,
                                                const float* __restrict__ lnw,
                                                const float* __restrict__ lnb,
                                                float* __restrict__ out, int N) {
    const int wv = threadIdx.x >> 6, lane = threadIdx.x & 63;
    const int node = blockIdx.x * 4 + wv;
    if (node >= N) return;
    const int start = nodestart[node], deg = nodedeg[node];
    const int half = lane >> 5, sl = lane & 31;

    float a0 = 0.f, a1 = 0.f, a2 = 0.f, a3 = 0.f;
    int e = 0;
    for (; e + 8 <= deg; e += 8) {
        unsigned g0 = sortedg[start + e + 0 + half];
        unsigned g1 = sortedg[start + e + 2 + half];
        unsigned g2 = sortedg[start + e + 4 + half];
        unsigned g3 = sortedg[start + e + 6 + half];
        uint2 p0 = m2[(size_t)g0 * 32 + sl];
        uint2 p1 = m2[(size_t)g1 * 32 + sl];
        uint2 p2 = m2[(size_t)g2 * 32 + sl];
        uint2 p3 = m2[(size_t)g3 * 32 + sl];
        a0 += bflo(p0.x) + bflo(p1.x) + bflo(p2.x) + bflo(p3.x);
        a1 += bfhi(p0.x) + bfhi(p1.x) + bfhi(p2.x) + bfhi(p3.x);
        a2 += bflo(p0.y) + bflo(p1.y) + bflo(p2.y) + bflo(p3.y);
        a3 += bfhi(p0.y) + bfhi(p1.y) + bfhi(p2.y) + bfhi(p3.y);
    }
    for (; e < deg; e += 2) {
        int idx = e + half;
        if (idx < deg) {
            uint2 p = m2[(size_t)sortedg[start + idx] * 32 + sl];
            a0 += bflo(p.x);
            a1 += bfhi(p.x);
            a2 += bflo(p.y);
            a3 += bfhi(p.y);
        }
    }
    // merge halves (each half summed a disjoint set of edges)
    a0 += __shfl_xor(a0, 32, 64);
    a1 += __shfl_xor(a1, 32, 64);
    a2 += __shfl_xor(a2, 32, 64);
    a3 += __shfl_xor(a3, 32, 64);
    float s = a0 + a1 + a2 + a3;
    float ss = a0 * a0 + a1 * a1 + a2 * a2 + a3 * a3;
#pragma unroll
    for (int o = 1; o < 32; o <<= 1) {
        s += __shfl_xor(s, o, 64);
        ss += __shfl_xor(ss, o, 64);
    }
    float mu = s * (1.0f / 128.0f);
    float var = ss * (1.0f / 128.0f) - mu * mu;
    float rstd = rsqrtf(var + LN_EPS);
    if (half == 0) {
        float4 w4 = ((const float4*)lnw)[sl];
        float4 b4 = ((const float4*)lnb)[sl];
        float4 o4;
        o4.x = (a0 - mu) * rstd * w4.x + b4.x;
        o4.y = (a1 - mu) * rstd * w4.y + b4.y;
        o4.z = (a2 - mu) * rstd * w4.z + b4.z;
        o4.w = (a3 - mu) * rstd * w4.w + b4.w;
        ((float4*)(out + (size_t)node * DD))[sl] = o4;
    }
}

extern "C" void kernel_launch(void* const* d_in, const int* in_sizes, int n_in,
                              void* d_out, int out_size, void* d_ws, size_t ws_size,
                              hipStream_t stream) {
    const float* feat = (const float*)d_in[0];
    const float* W    = (const float*)d_in[1];
    const float* Wf   = (const float*)d_in[2];
    const float* lnw  = (const float*)d_in[3];
    const float* lnb  = (const float*)d_in[4];
    const int* src    = (const int*)d_in[5];
    const int* dst    = (const int*)d_in[6];
    float* out = (float*)d_out;

    const int N = in_sizes[0] / DD;   // 100000
    const int E = in_sizes[5] / 4;    // 400000
    const int E4 = 4 * E;
    const int NB = (N + 127) >> 7;    // 782 bins
    const int NBLK = (E4 + CHUNK - 1) / CHUNK;  // 391
    const int NT = (N + 63) / 64;     // 1563 row tiles

    size_t off = 0;
    char* ws = (char*)d_ws;
    auto alloc = [&](size_t bytes) -> void* {
        void* p = ws + off;
        off += (bytes + 255) & ~(size_t)255;
        return p;
    };
    unsigned short* m     = (unsigned short*)alloc((size_t)4 * N * DD * 2);  // 102.4 MB
    unsigned short* featb = (unsigned short*)alloc((size_t)N * DD * 2);      // 25.6 MB
    unsigned short* wcat  = (unsigned short*)alloc((size_t)4 * 384 * 128 * 2);
    int* H      = (int*)alloc((size_t)NB * NBLK * 4);                        // 1.2 MB
    int* C      = (int*)alloc((size_t)NB * 4);
    int* binoff = (int*)alloc((size_t)(NB + 1) * 4);
    unsigned int* rec     = (unsigned int*)alloc((size_t)E4 * 4);            // 6.4 MB
    unsigned int* sortedg = (unsigned int*)alloc((size_t)E4 * 4);            // 6.4 MB
    int* nodestart = (int*)alloc((size_t)N * 4);
    int* nodedeg   = (int*)alloc((size_t)N * 4);
    if (off > ws_size) return;

    int n8 = N * DD / 8;
    k_pack_feat<<<(n8 + 255) / 256, 256, 0, stream>>>(feat, featb, n8);
    k_pack_w<<<(4 * 384 * 128 + 255) / 256, 256, 0, stream>>>(W, Wf, wcat);
    k_hist2<<<NBLK, 256, 0, stream>>>(dst, H, E4, NBLK, NB);
    k_scanbin<<<(NB * 64 + 255) / 256, 256, 0, stream>>>(H, C, NBLK, NB);
    k_scan<<<1, 1024, 0, stream>>>(C, binoff, NB);
    k_place2<<<NBLK, 256, 0, stream>>>(src, dst, H, binoff, rec, N, E, E4, NBLK, NB);
    k_sortout<<<NB, 256, 0, stream>>>(rec, binoff, sortedg, nodestart, nodedeg, N);
    dim3 gg(128, 4);
    k_gemm_film<<<gg, 256, 0, stream>>>(featb, wcat, m, N, NT);
    k_agg_ln<<<(N + 3) / 4, 256, 0, stream>>>(sortedg, nodestart, nodedeg,
                                              (const uint2*)m, lnw, lnb, out, N);
}